// Round 4
// baseline (463.962 us; speedup 1.0000x reference)
//
#include <hip/hip_runtime.h>
#include <math.h>

#define ALPHA 0.5f
#define BETA 0.9f
#define Bsz 512
#define Tsz 512
#define Dsz 256

__device__ __forceinline__ float wave_reduce_sum(float v) {
    v += __shfl_xor(v, 32, 64);
    v += __shfl_xor(v, 16, 64);
    v += __shfl_xor(v, 8, 64);
    v += __shfl_xor(v, 4, 64);
    v += __shfl_xor(v, 2, 64);
    v += __shfl_xor(v, 1, 64);
    return v;
}

__device__ __forceinline__ float wave_reduce_max(float v) {
    v = fmaxf(v, __shfl_xor(v, 32, 64));
    v = fmaxf(v, __shfl_xor(v, 16, 64));
    v = fmaxf(v, __shfl_xor(v, 8, 64));
    v = fmaxf(v, __shfl_xor(v, 4, 64));
    v = fmaxf(v, __shfl_xor(v, 2, 64));
    v = fmaxf(v, __shfl_xor(v, 1, 64));
    return v;
}

// Fused kernel, 512 threads (8 waves) per block, one block per batch row.
//   phase 0: ts/pad -> ok, tmax, count, lam (one t per thread)
//   phase 1: ascending-t stream over x[b] -> mean-pooled q   (HBM-bound; 16 waves/CU hide latency)
//   phase 2: Q = q@WQ.T ; qk = (Q@WK)/16  (split-half GEMVs, all 512 threads busy)
//   phase 3: barrier-free per-wave pass over own 64 rows: scores (stride-8 chunks,
//            3-step shuffle), g via __shfl broadcast, accum from L1-hot re-read.
//            x re-read is L3-hit (proven round 3: FETCH_SIZE == one pass).
//   phase 4: L = WV@xw, delta, M, T_event, p
__global__ __launch_bounds__(512, 4) void fused(const float* __restrict__ x,
                                                const float* __restrict__ ts,
                                                const unsigned char* __restrict__ pad,
                                                const float* __restrict__ WQ,
                                                const float* __restrict__ WK,
                                                const float* __restrict__ WV,
                                                const float* __restrict__ prevL,
                                                const float* __restrict__ prevM,
                                                const float* __restrict__ clsw,
                                                const float* __restrict__ clsb,
                                                float* __restrict__ out) {
    const int b = blockIdx.x;
    const int tid = threadIdx.x;
    const int w = tid >> 6, lane = tid & 63;
    const int rloc = lane >> 3;             // 0..7: row within this wave's 8-row group
    const int sub = lane & 7;               // 0..7: 8 threads per row (score phase)

    __shared__ float lamS[Tsz];             // phase 0: raw ts; then lam
    __shared__ float okS[Tsz];
    __shared__ float part[8][Dsz];          // reused: q partials / GEMV halves / acc partials
    __shared__ float qS[Dsz];
    __shared__ float QS[Dsz];
    __shared__ __align__(16) float qkS[Dsz];
    __shared__ float xwS[Dsz];
    __shared__ float EGS[16];
    __shared__ float red[16];
    __shared__ float red2[8];
    __shared__ float tmaxS, cntS;

    // ---- phase 0a: one t per thread ----
    {
        bool v = (pad[(size_t)b * Tsz + tid] == 0);
        float tv = ts[(size_t)b * Tsz + tid];
        okS[tid] = v ? 1.f : 0.f;
        lamS[tid] = tv;
        float lmax = v ? tv : -1e30f;
        float lcnt = v ? 1.f : 0.f;
        lmax = wave_reduce_max(lmax);
        lcnt = wave_reduce_sum(lcnt);
        if (lane == 0) { red[w] = lmax; red[8 + w] = lcnt; }
    }
    __syncthreads();
    if (tid == 0) {
        float m = -1e30f, c = 0.f;
        #pragma unroll
        for (int i = 0; i < 8; ++i) { m = fmaxf(m, red[i]); c += red[8 + i]; }
        tmaxS = m;
        cntS = fmaxf(c, 1.f);
    }
    __syncthreads();
    // ---- phase 0b: lam in place (same thread owns its t) ----
    {
        float dt = fmaxf(tmaxS - lamS[tid], 0.f) * (1.f / 86400.f);
        lamS[tid] = okS[tid] * __expf(-ALPHA * dt);
    }

    // ---- phase 1: q-sum; wave w owns rows [w*64, w*64+64), 4-row ILP ----
    const float* xb = x + (size_t)b * Tsz * Dsz;
    {
        float4 a0 = make_float4(0.f, 0.f, 0.f, 0.f);
        float4 a1 = a0, a2 = a0, a3 = a0;
        const int tbase = w * 64;
        for (int i = 0; i < 64; i += 4) {
            const int t = tbase + i;
            float4 x0 = *(const float4*)(xb + (size_t)(t + 0) * Dsz + lane * 4);
            float4 x1 = *(const float4*)(xb + (size_t)(t + 1) * Dsz + lane * 4);
            float4 x2 = *(const float4*)(xb + (size_t)(t + 2) * Dsz + lane * 4);
            float4 x3 = *(const float4*)(xb + (size_t)(t + 3) * Dsz + lane * 4);
            const float v0 = okS[t], v1 = okS[t + 1], v2 = okS[t + 2], v3 = okS[t + 3];
            a0.x += v0 * x0.x; a0.y += v0 * x0.y; a0.z += v0 * x0.z; a0.w += v0 * x0.w;
            a1.x += v1 * x1.x; a1.y += v1 * x1.y; a1.z += v1 * x1.z; a1.w += v1 * x1.w;
            a2.x += v2 * x2.x; a2.y += v2 * x2.y; a2.z += v2 * x2.z; a2.w += v2 * x2.w;
            a3.x += v3 * x3.x; a3.y += v3 * x3.y; a3.z += v3 * x3.z; a3.w += v3 * x3.w;
        }
        part[w][lane * 4 + 0] = (a0.x + a1.x) + (a2.x + a3.x);
        part[w][lane * 4 + 1] = (a0.y + a1.y) + (a2.y + a3.y);
        part[w][lane * 4 + 2] = (a0.z + a1.z) + (a2.z + a3.z);
        part[w][lane * 4 + 3] = (a0.w + a1.w) + (a2.w + a3.w);
    }
    __syncthreads();
    if (tid < Dsz) {
        float s = 0.f;
        #pragma unroll
        for (int w2 = 0; w2 < 8; ++w2) s += part[w2][tid];
        qS[tid] = s / cntS;
    }
    __syncthreads();

    // ---- phase 2a: Q[i] = sum_d q[d]*WQ[i,d], split across two halves of d ----
    {
        const int i = tid & 255, half = tid >> 8;
        const float* wq = WQ + (size_t)i * Dsz + half * 128;
        const float* qh = qS + half * 128;
        float acc = 0.f;
        #pragma unroll 4
        for (int d4 = 0; d4 < 128; d4 += 4) {
            float4 wv = *(const float4*)(wq + d4);
            acc += wv.x * qh[d4] + wv.y * qh[d4 + 1] + wv.z * qh[d4 + 2] + wv.w * qh[d4 + 3];
        }
        part[half][i] = acc;
    }
    __syncthreads();
    if (tid < Dsz) QS[tid] = part[0][tid] + part[1][tid];
    __syncthreads();

    // ---- phase 2b: qk[d] = (sum_e Q[e]*WK[e,d])/16, split across two halves of e ----
    {
        const int d = tid & 255, half = tid >> 8;
        const int e0 = half * 128;
        float v0 = 0.f, v1 = 0.f, v2 = 0.f, v3 = 0.f;
        #pragma unroll 4
        for (int e = e0; e < e0 + 128; e += 4) {
            v0 += QS[e + 0] * WK[(size_t)(e + 0) * Dsz + d];
            v1 += QS[e + 1] * WK[(size_t)(e + 1) * Dsz + d];
            v2 += QS[e + 2] * WK[(size_t)(e + 2) * Dsz + d];
            v3 += QS[e + 3] * WK[(size_t)(e + 3) * Dsz + d];
        }
        part[half][d] = (v0 + v1) + (v2 + v3);
    }
    __syncthreads();
    if (tid < Dsz) qkS[tid] = (part[0][tid] + part[1][tid]) * 0.0625f;
    __syncthreads();

    // ---- phase 3: per-wave, barrier-free; wave w owns rows [w*64, w*64+64) ----
    float4 qkr[8];
    #pragma unroll
    for (int jj = 0; jj < 8; ++jj)
        qkr[jj] = *(const float4*)(&qkS[(jj * 8 + sub) << 2]);

    float4 acc = make_float4(0.f, 0.f, 0.f, 0.f);
    float E = 0.f, G = 0.f;   // each row counted 8x (identical across subs); /8 at the end
    {
        const int rowbase = w * 64;
        for (int gi = 7; gi >= 0; --gi) {          // descending within region
            const int base = rowbase + gi * 8;
            const int r = base + rloc;
            const float* rp = xb + (size_t)r * Dsz;
            float s = 0.f;
            #pragma unroll
            for (int jj = 0; jj < 8; ++jj) {
                const float4 xv = *(const float4*)(rp + ((jj * 8 + sub) << 2));
                s += xv.x * qkr[jj].x + xv.y * qkr[jj].y + xv.z * qkr[jj].z + xv.w * qkr[jj].w;
            }
            s += __shfl_xor(s, 1, 64);
            s += __shfl_xor(s, 2, 64);
            s += __shfl_xor(s, 4, 64);
            const float e = okS[r] * __expf(s);
            const float g = lamS[r] * e;
            E += e; G += g;
            // broadcast g of each of this wave's 8 rows; accum from L1-hot re-read
            #pragma unroll
            for (int k = 0; k < 8; ++k) {
                const float gk = __shfl(g, k * 8, 64);
                const float4 xa = *(const float4*)(xb + (size_t)(base + k) * Dsz + lane * 4);
                acc.x += gk * xa.x; acc.y += gk * xa.y; acc.z += gk * xa.z; acc.w += gk * xa.w;
            }
        }
    }
    part[w][lane * 4 + 0] = acc.x;
    part[w][lane * 4 + 1] = acc.y;
    part[w][lane * 4 + 2] = acc.z;
    part[w][lane * 4 + 3] = acc.w;
    {
        float Ew = wave_reduce_sum(E) * 0.125f;
        float Gw = wave_reduce_sum(G) * 0.125f;
        if (lane == 0) { EGS[w] = Ew; EGS[8 + w] = Gw; }
    }
    __syncthreads();
    if (tid < Dsz) {
        float Et = 0.f, Gt = 0.f;
        #pragma unroll
        for (int i = 0; i < 8; ++i) { Et += EGS[i]; Gt += EGS[8 + i]; }
        float denom = Gt + 1e-8f * Et;   // softmax denominators cancel
        float accd = 0.f;
        #pragma unroll
        for (int w2 = 0; w2 < 8; ++w2) accd += part[w2][tid];
        xwS[tid] = (denom > 0.f) ? accd / denom : 0.f;
    }
    __syncthreads();

    // ---- phase 4: Le[i] = sum_d WV[i,d]*xw[d], split halves; then delta/M/p ----
    {
        const int i = tid & 255, half = tid >> 8;
        const float* wv = WV + (size_t)i * Dsz + half * 128;
        const float* xh = xwS + half * 128;
        float a = 0.f;
        #pragma unroll 4
        for (int d4 = 0; d4 < 128; d4 += 4) {
            float4 wvv = *(const float4*)(wv + d4);
            a += wvv.x * xh[d4] + wvv.y * xh[d4 + 1] + wvv.z * xh[d4 + 2] + wvv.w * xh[d4 + 3];
        }
        part[half][i] = a;
    }
    __syncthreads();

    float Le = 0.f, delta = 0.f, pp = 0.f;
    if (tid < Dsz) {
        Le = part[0][tid] + part[1][tid];
        delta = Le - prevL[(size_t)b * Dsz + tid];
        pp = Le * clsw[tid] + delta * clsw[Dsz + tid];
    }
    float ssq = wave_reduce_sum(delta * delta);   // waves 4..7 contribute 0
    float psum = wave_reduce_sum(pp);
    if (lane == 0) { red[w] = ssq; red2[w] = psum; }
    __syncthreads();

    if (tid < Dsz) {
        float sr = 0.f;
        #pragma unroll
        for (int i = 0; i < 8; ++i) sr += red[i];
        float nrm = sqrtf(sr);
        float M = BETA * prevM[b] + (1.f - BETA) * nrm;

        float* out_p = out;
        float* out_T = out + Bsz;
        float* out_L = out + Bsz + (size_t)Bsz * (2 * Dsz + 1);
        float* out_M = out + Bsz + (size_t)Bsz * (2 * Dsz + 1) + (size_t)Bsz * Dsz;

        out_T[(size_t)b * (2 * Dsz + 1) + tid] = Le;
        out_T[(size_t)b * (2 * Dsz + 1) + Dsz + tid] = delta;
        out_L[(size_t)b * Dsz + tid] = Le;
        if (tid == 0) {
            float ps = 0.f;
            #pragma unroll
            for (int i = 0; i < 8; ++i) ps += red2[i];
            float p = ps + M * clsw[2 * Dsz] + clsb[0];
            out_p[b] = p;
            out_T[(size_t)b * (2 * Dsz + 1) + 2 * Dsz] = M;
            out_M[b] = M;
        }
    }
}

extern "C" void kernel_launch(void* const* d_in, const int* in_sizes, int n_in,
                              void* d_out, int out_size, void* d_ws, size_t ws_size,
                              hipStream_t stream) {
    const float* x     = (const float*)d_in[0];
    const float* ts    = (const float*)d_in[1];
    const float* prevL = (const float*)d_in[2];
    const float* prevM = (const float*)d_in[3];
    const unsigned char* pad = (const unsigned char*)d_in[4];
    const float* WQ    = (const float*)d_in[5];
    const float* WK    = (const float*)d_in[6];
    const float* WV    = (const float*)d_in[7];
    const float* clsw  = (const float*)d_in[8];
    const float* clsb  = (const float*)d_in[9];

    (void)d_ws; (void)ws_size;  // fully fused: no workspace needed

    fused<<<Bsz, 512, 0, stream>>>(x, ts, pad, WQ, WK, WV, prevL, prevM, clsw, clsb,
                                   (float*)d_out);
}